// Round 16
// baseline (103.154 us; speedup 1.0000x reference)
//
#include <hip/hip_runtime.h>

// VQ-VAE vector quantization via bf16-split MFMA, codes-in-REGISTERS:
// Round 16. A = codes, held in VGPRs for the whole kernel (8 waves x 4
// ntiles x (hi 16 + lo 16 + nh 4) = 144 VGPR); B = x fragments staged ONCE
// to LDS (64KB). Main loop: 8 q-subtiles x {8 ds_read_b128 + 52 MFMA},
// ZERO barriers / GLL / vmcnt. Lane-local argmax (6-bit inv id in mantissa),
// cross-wave reduce via 16KB LDS pass at the end.
// ws layout (floats):
//   [0..31]          loss partials
//   [2048..34815]    hist partials 32 x 1024
//   [34816..108543]  packed code frags: [w 8][nt 4][f 9][half 2][32 codes][16B]
//                    f 0-3 hi kf, 4-7 lo kf, 8 nh {nh0,nh1,nh2,0...;zeros}
//   [110592..176127] qidx as ushort[131072]

typedef __attribute__((ext_vector_type(8))) short short8;
typedef __attribute__((ext_vector_type(16))) float f32x16;

#define LOSS_OFF 0
#define PART_OFF 2048
#define PACKED_OFF 34816
#define QIDX_OFF 110592
#define NPART 32

__device__ __forceinline__ unsigned short bf16_rne(float v, float& rest) {
  const unsigned u = __float_as_uint(v);
  const unsigned r = u + 0x7fffu + ((u >> 16) & 1u);
  const unsigned short h = (unsigned short)(r >> 16);
  rest = v - __uint_as_float((unsigned)h << 16);
  return h;
}

__global__ void vq_pack(const float* __restrict__ cb0, const float* __restrict__ cb1,
                        float* __restrict__ ws) {
  const int c = blockIdx.x * 256 + threadIdx.x;  // 0..1023
  if (c < NPART) ws[LOSS_OFF + c] = 0.0f;
#pragma unroll
  for (int p = 0; p < NPART; ++p) ws[PART_OFF + p * 1024 + c] = 0.0f;
  const float* row = (c < 512) ? (cb0 + (size_t)c * 64) : (cb1 + (size_t)(c - 512) * 64);
  float v[64];
  float nrm = 0.f;
#pragma unroll
  for (int d = 0; d < 64; d += 4) {
    const float4 f = *(const float4*)(row + d);
    v[d] = f.x; v[d + 1] = f.y; v[d + 2] = f.z; v[d + 3] = f.w;
    nrm += f.x * f.x + f.y * f.y + f.z * f.z + f.w * f.w;
  }
  unsigned short hi[64], lo[64];
#pragma unroll
  for (int d = 0; d < 64; ++d) {
    float rest, dump;
    hi[d] = bf16_rne(v[d], rest);
    lo[d] = bf16_rne(rest, dump);
  }
  const int w = c >> 7, nt = (c >> 5) & 3, cl = c & 31;
  float* fb = ws + PACKED_OFF + (size_t)((w * 4 + nt) * 9) * 256 + cl * 4;
#pragma unroll
  for (int t = 0; t < 2; ++t)
#pragma unroll
    for (int kf = 0; kf < 4; ++kf)
#pragma unroll
      for (int hf = 0; hf < 2; ++hf) {
        short8 gr;
#pragma unroll
        for (int j = 0; j < 8; ++j) {
          const int d = kf * 16 + hf * 8 + j;
          gr[j] = (short)(t ? lo[d] : hi[d]);
        }
        *(short8*)(fb + (t * 4 + kf) * 256 + hf * 128) = gr;
      }
  {  // f=8: nh 3-term split (half 0), zeros (half 1)
    const float nh = -0.5f * nrm;
    float r1, r2, dump;
    const unsigned short n0 = bf16_rne(nh, r1);
    const unsigned short n1 = bf16_rne(r1, r2);
    const unsigned short n2 = bf16_rne(r2, dump);
    short8 g = {(short)n0, (short)n1, (short)n2, 0, 0, 0, 0, 0};
    *(short8*)(fb + 8 * 256) = g;
    short8 zz = {0, 0, 0, 0, 0, 0, 0, 0};
    *(short8*)(fb + 8 * 256 + 128) = zz;
  }
}

__global__ __launch_bounds__(512, 2) void vq_dist(
    const float* __restrict__ xin, const int* __restrict__ idxp,
    float* __restrict__ ws) {
  __shared__ char smem[67584];  // 64KB x-frags (reduce scratch reuses) + 2KB xx
  float* xxp = (float*)(smem + 65536);
  const int tid = threadIdx.x;
  const int w = tid >> 6;      // wave 0..7: owns codes w*128..+127
  const int l = tid & 63;
  const int half = l >> 5;
  const int col = l & 31;
  const int blk = blockIdx.x;  // 512 blocks x 256 q
  const int bb = blk >> 4;
  const int hw0 = (blk & 15) << 8;
  const int nc = (*idxp == 0) ? 512 : 1024;
  const bool wact = (w * 128) < nc;

  // ---- code fragments -> registers (persistent; coalesced 1KB loads)
  short8 Ah[4][4], Al[4][4], An[4];
  if (wact) {
    const char* pkb = (const char*)(ws + PACKED_OFF) + (size_t)w * 36864 + l * 16;
#pragma unroll
    for (int nt = 0; nt < 4; ++nt) {
      const char* base = pkb + nt * 9216;
#pragma unroll
      for (int kf = 0; kf < 4; ++kf) Ah[nt][kf] = *(const short8*)(base + kf * 1024);
#pragma unroll
      for (int kf = 0; kf < 4; ++kf) Al[nt][kf] = *(const short8*)(base + (4 + kf) * 1024);
      An[nt] = *(const short8*)(base + 8 * 1024);
    }
  }

  // ---- x -> LDS as ready B-fragments (one pass, coalesced global reads)
  {
    const int qloc = tid & 255;
    const int dbase = (tid >> 8) * 32;
    const float* xg = xin + (((size_t)(bb * 64 + dbase)) << 12) + hw0 + qloc;
    const int s = qloc >> 5;
    const int qm = qloc & 31;
    float xs2 = 0.f;
#pragma unroll
    for (int g = 0; g < 4; ++g) {  // d = dbase + g*8 + j
      float v[8];
#pragma unroll
      for (int j = 0; j < 8; ++j) v[j] = xg[((size_t)(g * 8 + j)) << 12];
      short8 hi8, lo8;
#pragma unroll
      for (int j = 0; j < 8; ++j) {
        float rest, dump;
        hi8[j] = (short)bf16_rne(v[j], rest);
        lo8[j] = (short)bf16_rne(rest, dump);
        xs2 += v[j] * v[j];
      }
      const int kf = (dbase >> 4) + (g >> 1);
      const int hf = g & 1;
      char* wb = smem + (size_t)(s * 8 + kf) * 1024 + (hf * 32 + qm) * 16;
      *(short8*)wb = hi8;
      *(short8*)(wb + 4096) = lo8;  // lo frag ids are +4
    }
    xxp[tid] = xs2;
  }
  // x~ extension for nh MFMA: k 0..2 = 1.0 (half 0 only)
  short8 xnh;
#pragma unroll
  for (int j = 0; j < 8; ++j) xnh[j] = (short)((half == 0 && j < 3) ? 0x3F80 : 0);
  const f32x16 ZV = (f32x16)0.0f;
  __syncthreads();  // x-frags + xx visible; the ONLY pre-loop barrier

  // best[s]: packed score, low 6 mantissa bits = 63-(nt*16+r); fmax prefers
  // higher score then smaller (nt,r) => smaller code. <=1e-3 perturbation.
  float best[8];
#pragma unroll
  for (int s = 0; s < 8; ++s) best[s] = -3.4e38f;

  if (wact) {
#pragma unroll
    for (int s = 0; s < 8; ++s) {
      const char* xb = smem + (size_t)s * 8192 + l * 16;
      short8 xh[4], xl[4];
#pragma unroll
      for (int kf = 0; kf < 4; ++kf) xh[kf] = *(const short8*)(xb + kf * 1024);
#pragma unroll
      for (int kf = 0; kf < 4; ++kf) xl[kf] = *(const short8*)(xb + 4096 + kf * 1024);
      {  // ntile pair (0,1)
        f32x16 a0 = __builtin_amdgcn_mfma_f32_32x32x16_bf16(An[0], xnh, ZV, 0, 0, 0);
        f32x16 a1 = __builtin_amdgcn_mfma_f32_32x32x16_bf16(An[1], xnh, ZV, 0, 0, 0);
#pragma unroll
        for (int kf = 0; kf < 4; ++kf) {
          a0 = __builtin_amdgcn_mfma_f32_32x32x16_bf16(Ah[0][kf], xh[kf], a0, 0, 0, 0);
          a1 = __builtin_amdgcn_mfma_f32_32x32x16_bf16(Ah[1][kf], xh[kf], a1, 0, 0, 0);
          a0 = __builtin_amdgcn_mfma_f32_32x32x16_bf16(Ah[0][kf], xl[kf], a0, 0, 0, 0);
          a1 = __builtin_amdgcn_mfma_f32_32x32x16_bf16(Ah[1][kf], xl[kf], a1, 0, 0, 0);
          a0 = __builtin_amdgcn_mfma_f32_32x32x16_bf16(Al[0][kf], xh[kf], a0, 0, 0, 0);
          a1 = __builtin_amdgcn_mfma_f32_32x32x16_bf16(Al[1][kf], xh[kf], a1, 0, 0, 0);
        }
#pragma unroll
        for (int r = 0; r < 16; ++r) {
          const float p0 = __uint_as_float((__float_as_uint(a0[r]) & 0xFFFFFFC0u) | (unsigned)(63 - r));
          const float p1 = __uint_as_float((__float_as_uint(a1[r]) & 0xFFFFFFC0u) | (unsigned)(47 - r));
          best[s] = fmaxf(best[s], fmaxf(p0, p1));
        }
      }
      {  // ntile pair (2,3)
        f32x16 a0 = __builtin_amdgcn_mfma_f32_32x32x16_bf16(An[2], xnh, ZV, 0, 0, 0);
        f32x16 a1 = __builtin_amdgcn_mfma_f32_32x32x16_bf16(An[3], xnh, ZV, 0, 0, 0);
#pragma unroll
        for (int kf = 0; kf < 4; ++kf) {
          a0 = __builtin_amdgcn_mfma_f32_32x32x16_bf16(Ah[2][kf], xh[kf], a0, 0, 0, 0);
          a1 = __builtin_amdgcn_mfma_f32_32x32x16_bf16(Ah[3][kf], xh[kf], a1, 0, 0, 0);
          a0 = __builtin_amdgcn_mfma_f32_32x32x16_bf16(Ah[2][kf], xl[kf], a0, 0, 0, 0);
          a1 = __builtin_amdgcn_mfma_f32_32x32x16_bf16(Ah[3][kf], xl[kf], a1, 0, 0, 0);
          a0 = __builtin_amdgcn_mfma_f32_32x32x16_bf16(Al[2][kf], xh[kf], a0, 0, 0, 0);
          a1 = __builtin_amdgcn_mfma_f32_32x32x16_bf16(Al[3][kf], xh[kf], a1, 0, 0, 0);
        }
#pragma unroll
        for (int r = 0; r < 16; ++r) {
          const float p0 = __uint_as_float((__float_as_uint(a0[r]) & 0xFFFFFFC0u) | (unsigned)(31 - r));
          const float p1 = __uint_as_float((__float_as_uint(a1[r]) & 0xFFFFFFC0u) | (unsigned)(15 - r));
          best[s] = fmaxf(best[s], fmaxf(p0, p1));
        }
      }
    }
  }

  __syncthreads();  // all waves done with x-frags; scratch may overwrite
  float* scoreL = (float*)smem;       // [8][256]
  int* codeL = (int*)(smem + 8192);   // [8][256]
  if (wact) {
#pragma unroll
    for (int s = 0; s < 8; ++s) {
      const unsigned u = __float_as_uint(best[s]);
      const int iid = 63 - (int)(u & 63u);
      const int nt = iid >> 4, r = iid & 15;
      const int rrow = (r & 3) + 8 * (r >> 2) + 4 * half;
      int code = w * 128 + nt * 32 + rrow;
      float clean = __uint_as_float(u & 0xFFFFFFC0u);
      const float ocl = __shfl_xor(clean, 32);
      const int oc = __shfl_xor(code, 32);
      if (ocl > clean || (ocl == clean && oc < code)) { clean = ocl; code = oc; }
      if (half == 0) {
        scoreL[w * 256 + s * 32 + col] = clean;
        codeL[w * 256 + s * 32 + col] = code;
      }
    }
  }
  __syncthreads();

  const int nw = nc >> 7;  // 4 or 8 candidate waves
  if (tid < 256) {
    float bs = scoreL[tid];
    int bc = codeL[tid];
#pragma unroll
    for (int ww = 1; ww < 8; ++ww) {
      if (ww >= nw) break;
      const float sc = scoreL[ww * 256 + tid];
      const int cd = codeL[ww * 256 + tid];
      if (sc > bs || (sc == bs && cd < bc)) { bs = sc; bc = cd; }
    }
    ((unsigned short*)(ws + QIDX_OFF))[bb * 4096 + hw0 + tid] = (unsigned short)bc;
    float ls = (xxp[tid] + xxp[tid + 256]) - 2.0f * bs;  // ||x-c*||^2
#pragma unroll
    for (int mk = 1; mk < 64; mk <<= 1) ls += __shfl_xor(ls, mk);
    if ((tid & 63) == 0) atomicAdd(&ws[LOSS_OFF + (blk & (NPART - 1))], ls);
  }
}

__global__ __launch_bounds__(256) void vq_out(
    const float* __restrict__ cb0, const float* __restrict__ cb1,
    float* __restrict__ out, float* __restrict__ ws) {
  const int tid = threadIdx.x;
  const int blk = blockIdx.x;  // 512 blocks x 256 q
  const int bb = blk >> 4;
  const int hw0 = (blk & 15) << 8;
  const int q = bb * 4096 + hw0 + tid;
  const int ci = (int)((const unsigned short*)(ws + QIDX_OFF))[q];
  atomicAdd(ws + PART_OFF + (size_t)(blk & (NPART - 1)) * 1024 + ci, 1.0f);
  const float* crow = (ci < 512) ? (cb0 + (size_t)ci * 64) : (cb1 + (size_t)(ci - 512) * 64);
  float* ob = out + (((size_t)(bb * 64)) << 12) + hw0 + tid;
#pragma unroll
  for (int d4 = 0; d4 < 16; ++d4) {
    const float4 f = *(const float4*)(crow + d4 * 4);
    ob[((size_t)(d4 * 4 + 0)) << 12] = f.x;
    ob[((size_t)(d4 * 4 + 1)) << 12] = f.y;
    ob[((size_t)(d4 * 4 + 2)) << 12] = f.z;
    ob[((size_t)(d4 * 4 + 3)) << 12] = f.w;
  }
}

__global__ void vq_final(const float* __restrict__ ws, float* __restrict__ out) {
  __shared__ float sred[256];
  const int t = threadIdx.x;
  float h = 0.f;
#pragma unroll
  for (int i = t; i < 1024; i += 256) {
    float s = 0.f;
#pragma unroll
    for (int p = 0; p < NPART; ++p) s += ws[PART_OFF + p * 1024 + i];
    const float avg = s * (1.0f / 131072.0f);
    h += avg * logf(avg + 1e-10f);
  }
  sred[t] = h;
  __syncthreads();
  for (int s2 = 128; s2 > 0; s2 >>= 1) {
    if (t < s2) sred[t] += sred[t + s2];
    __syncthreads();
  }
  if (t == 0) {
    float lsum = 0.f;
#pragma unroll
    for (int p = 0; p < NPART; ++p) lsum += ws[LOSS_OFF + p];
    out[8388608] = 1.25f * lsum * (1.0f / 8388608.0f);
    out[8388609] = expf(-sred[0]);
  }
}

extern "C" void kernel_launch(void* const* d_in, const int* in_sizes, int n_in,
                              void* d_out, int out_size, void* d_ws, size_t ws_size,
                              hipStream_t stream) {
  (void)in_sizes; (void)n_in; (void)out_size; (void)ws_size;
  const float* xin = (const float*)d_in[0];
  const float* cb0 = (const float*)d_in[1];
  const float* cb1 = (const float*)d_in[2];
  const int* idxp = (const int*)d_in[3];
  float* out = (float*)d_out;
  float* ws = (float*)d_ws;

  vq_pack<<<4, 256, 0, stream>>>(cb0, cb1, ws);
  vq_dist<<<512, 512, 0, stream>>>(xin, idxp, ws);
  vq_out<<<512, 256, 0, stream>>>(cb0, cb1, out, ws);
  vq_final<<<1, 256, 0, stream>>>(ws, out);
}

// Round 17
// 77.641 us; speedup vs baseline: 1.3286x; 1.3286x over previous
//
#include <hip/hip_runtime.h>

// VQ-VAE vector quantization via bf16-split MFMA, SWAPPED operands (r15 base):
// A = codes (LDS), B = x (regs) -> lane-local argmax. score = c~.x~ with
// nh granule folded into the GEMM (zero C-init). Round 17:
//  - vq_out FOLDED into vq_dist (qidx stays in LDS; gather+NCHW write+hist
//    in the same kernel) -> one less dispatch + no qidx roundtrip
//  - stage(0)/stage(1) issued BEFORE x prologue (GLL latency hides under
//    bf16-split conversion; compiler's x-waits retire them for free)
//  - setprio(1) around MFMA cluster (2 independent blocks/CU = role diversity)
// ws layout (floats):
//   [0..31]          loss partials
//   [2048..34815]    hist partials 32 x 1024
//   [34816..133119]  packed codes: 16 chunks x 6144 floats (24KB):
//                    [24 granules][64 codes][16B]; g0-7 hi, g8-15 lo,
//                    g16 = [nh0,nh1,nh2,0...], g17 = zeros, g18-23 pad

typedef __attribute__((ext_vector_type(8))) short short8;
typedef __attribute__((ext_vector_type(16))) float f32x16;

#define LOSS_OFF 0
#define PART_OFF 2048
#define PACKED_OFF 34816
#define NPART 32
#define CHUNK_B 24576

#define GLL16(gsrc, ldst)                                                      \
  __builtin_amdgcn_global_load_lds(                                            \
      (const __attribute__((address_space(1))) void*)(gsrc),                   \
      (__attribute__((address_space(3))) void*)(ldst), 16, 0, 0)

__device__ __forceinline__ unsigned short bf16_rne(float v, float& rest) {
  const unsigned u = __float_as_uint(v);
  const unsigned r = u + 0x7fffu + ((u >> 16) & 1u);
  const unsigned short h = (unsigned short)(r >> 16);
  rest = v - __uint_as_float((unsigned)h << 16);
  return h;
}

__global__ void vq_pack(const float* __restrict__ cb0, const float* __restrict__ cb1,
                        float* __restrict__ ws) {
  const int c = blockIdx.x * 256 + threadIdx.x;  // 0..1023
  if (c < NPART) ws[LOSS_OFF + c] = 0.0f;
#pragma unroll
  for (int p = 0; p < NPART; ++p) ws[PART_OFF + p * 1024 + c] = 0.0f;
  const float* row = (c < 512) ? (cb0 + (size_t)c * 64) : (cb1 + (size_t)(c - 512) * 64);
  float v[64];
  float nrm = 0.f;
#pragma unroll
  for (int d = 0; d < 64; d += 4) {
    const float4 f = *(const float4*)(row + d);
    v[d] = f.x; v[d + 1] = f.y; v[d + 2] = f.z; v[d + 3] = f.w;
    nrm += f.x * f.x + f.y * f.y + f.z * f.z + f.w * f.w;
  }
  unsigned short hi[64], lo[64];
#pragma unroll
  for (int d = 0; d < 64; ++d) {
    float rest, dump;
    hi[d] = bf16_rne(v[d], rest);
    lo[d] = bf16_rne(rest, dump);
  }
  float* base = ws + PACKED_OFF + (size_t)(c >> 6) * 6144 + (c & 63) * 4;
#pragma unroll
  for (int g = 0; g < 16; ++g) {
    short8 gr;
#pragma unroll
    for (int e = 0; e < 8; ++e)
      gr[e] = (short)((g < 8) ? hi[g * 8 + e] : lo[(g - 8) * 8 + e]);
    *(short8*)(base + g * 256) = gr;
  }
  {  // g16 = 3-term bf16 split of -0.5||c||^2 ; g17 = zeros (half-1 k-slice)
    const float nh = -0.5f * nrm;
    float r1, r2, dump;
    const unsigned short n0 = bf16_rne(nh, r1);
    const unsigned short n1 = bf16_rne(r1, r2);
    const unsigned short n2 = bf16_rne(r2, dump);
    short8 g16 = {(short)n0, (short)n1, (short)n2, 0, 0, 0, 0, 0};
    *(short8*)(base + 16 * 256) = g16;
    short8 zz = {0, 0, 0, 0, 0, 0, 0, 0};
    *(short8*)(base + 17 * 256) = zz;
  }
}

__global__ __launch_bounds__(256, 2) void vq_dist(
    const float* __restrict__ xin, const int* __restrict__ idxp,
    const float* __restrict__ cb0, const float* __restrict__ cb1,
    float* __restrict__ out, float* __restrict__ ws) {
  __shared__ char ring[73728];  // 3 x 24KB ring; reused as qidx after K-loop
  const int tid = threadIdx.x;
  const int w = tid >> 6;      // wave 0..3, owns q w*64..+63
  const int l = tid & 63;
  const int half = l >> 5;
  const int col = l & 31;      // this lane's q within its 32-col tile
  const int blk = blockIdx.x;  // 512 blocks x 256 q
  const int bb = blk >> 4;
  const int hw0 = (blk & 15) << 8;
  const int nch = (*idxp == 0) ? 8 : 16;
  const char* pk = (const char*)(ws + PACKED_OFF);

  // stage chunk: 24KB over 4 waves -> 6 x 1KB GLL per wave
  auto stage = [&](int ch, int buf) {
    const char* src = pk + (size_t)ch * CHUNK_B + w * 6144 + l * 16;
    char* dst = ring + buf * CHUNK_B + w * 6144;
#pragma unroll
    for (int i = 0; i < 6; ++i) GLL16(src + i * 1024, dst + i * 1024);
  };
  // issue chunk 0/1 DMAs FIRST: their latency hides under the x prologue
  stage(0, 0);
  stage(1, 1);

  // ---- x: direct global->reg, B-fragments for 2 q-col-tiles
  short8 xh[2][4], xl[2][4];
  float xx[2];
#pragma unroll
  for (int m = 0; m < 2; ++m) {
    float vv[4][8];
    const float* xb =
        xin + ((size_t)(bb * 64 + half * 8)) * 4096 + hw0 + w * 64 + m * 32 + col;
#pragma unroll
    for (int kf = 0; kf < 4; ++kf)
#pragma unroll
      for (int j = 0; j < 8; ++j)
        vv[kf][j] = xb[((size_t)(kf * 16 + j)) * 4096];
    float s = 0.f;
#pragma unroll
    for (int kf = 0; kf < 4; ++kf)
#pragma unroll
      for (int j = 0; j < 8; ++j) {
        const float v = vv[kf][j];
        float rest, dump;
        xh[m][kf][j] = (short)bf16_rne(v, rest);
        xl[m][kf][j] = (short)bf16_rne(rest, dump);
        s += v * v;
      }
    s += __shfl_xor(s, 32);  // lanes l, l^32: same q, complementary dims
    xx[m] = s;
  }
  // x~ extension fragment for the nh-granule MFMA: k=0..2 = 1.0 (half-0)
  short8 xnh;
#pragma unroll
  for (int j = 0; j < 8; ++j)
    xnh[j] = (short)((half == 0 && j < 3) ? 0x3F80 : 0);
  const f32x16 ZV = (f32x16)0.0f;  // persistent zero C-input

  // best[m][r]: packed score, low 5 mantissa bits = 31-(2*chunk+n); fmax
  // prefers smaller code on near-ties; r identity kept by register position.
  float best[2][16];
#pragma unroll
  for (int m = 0; m < 2; ++m)
#pragma unroll
    for (int r = 0; r < 16; ++r) best[m][r] = -3.4e38f;

  for (int i = 0; i < nch; ++i) {
    if (i < nch - 1) {
      asm volatile("s_waitcnt vmcnt(6)" ::: "memory");  // chunk i landed
    } else {
      asm volatile("s_waitcnt vmcnt(0)" ::: "memory");
    }
    __builtin_amdgcn_s_barrier();  // chunk i resident; chunk i-1 consumed
    if (i + 2 < nch) stage(i + 2, (i + 2) % 3);  // refills buf[(i-1)%3]: safe
    const char* bufp = ring + (i % 3) * CHUNK_B;
    const char* tb0 = bufp + col * 16;          // n=0 code tile, row = col
    const char* tb1 = bufp + (32 + col) * 16;   // n=1 code tile

    __builtin_amdgcn_s_setprio(1);
    // nh-granule MFMAs initialize the accumulators (C = ZV)
    const short8 An0 = *(const short8*)(tb0 + (16 + half) * 1024);
    const short8 An1 = *(const short8*)(tb1 + (16 + half) * 1024);
    f32x16 a00 = __builtin_amdgcn_mfma_f32_32x32x16_bf16(An0, xnh, ZV, 0, 0, 0);
    f32x16 a01 = __builtin_amdgcn_mfma_f32_32x32x16_bf16(An1, xnh, ZV, 0, 0, 0);
    f32x16 a10 = __builtin_amdgcn_mfma_f32_32x32x16_bf16(An0, xnh, ZV, 0, 0, 0);
    f32x16 a11 = __builtin_amdgcn_mfma_f32_32x32x16_bf16(An1, xnh, ZV, 0, 0, 0);
#pragma unroll
    for (int kf = 0; kf < 4; ++kf) {
      const short8 Ah0 = *(const short8*)(tb0 + (2 * kf + half) * 1024);
      const short8 Ah1 = *(const short8*)(tb1 + (2 * kf + half) * 1024);
      const short8 Al0 = *(const short8*)(tb0 + (8 + 2 * kf + half) * 1024);
      const short8 Al1 = *(const short8*)(tb1 + (8 + 2 * kf + half) * 1024);
      a00 = __builtin_amdgcn_mfma_f32_32x32x16_bf16(Ah0, xh[0][kf], a00, 0, 0, 0);
      a01 = __builtin_amdgcn_mfma_f32_32x32x16_bf16(Ah1, xh[0][kf], a01, 0, 0, 0);
      a10 = __builtin_amdgcn_mfma_f32_32x32x16_bf16(Ah0, xh[1][kf], a10, 0, 0, 0);
      a11 = __builtin_amdgcn_mfma_f32_32x32x16_bf16(Ah1, xh[1][kf], a11, 0, 0, 0);
      a00 = __builtin_amdgcn_mfma_f32_32x32x16_bf16(Ah0, xl[0][kf], a00, 0, 0, 0);
      a01 = __builtin_amdgcn_mfma_f32_32x32x16_bf16(Ah1, xl[0][kf], a01, 0, 0, 0);
      a10 = __builtin_amdgcn_mfma_f32_32x32x16_bf16(Ah0, xl[1][kf], a10, 0, 0, 0);
      a11 = __builtin_amdgcn_mfma_f32_32x32x16_bf16(Ah1, xl[1][kf], a11, 0, 0, 0);
      a00 = __builtin_amdgcn_mfma_f32_32x32x16_bf16(Al0, xh[0][kf], a00, 0, 0, 0);
      a01 = __builtin_amdgcn_mfma_f32_32x32x16_bf16(Al1, xh[0][kf], a01, 0, 0, 0);
      a10 = __builtin_amdgcn_mfma_f32_32x32x16_bf16(Al0, xh[1][kf], a10, 0, 0, 0);
      a11 = __builtin_amdgcn_mfma_f32_32x32x16_bf16(Al1, xh[1][kf], a11, 0, 0, 0);
    }
    __builtin_amdgcn_s_setprio(0);

    // ---- lane-local running argmax (codes on rows -> per-lane regs)
    const unsigned sid0 = (unsigned)(31 - 2 * i);
    const unsigned sid1 = (unsigned)(30 - 2 * i);
#pragma unroll
    for (int r = 0; r < 16; ++r) {
      const float p00 = __uint_as_float((__float_as_uint(a00[r]) & 0xFFFFFFE0u) | sid0);
      const float p01 = __uint_as_float((__float_as_uint(a01[r]) & 0xFFFFFFE0u) | sid1);
      best[0][r] = fmaxf(fmaxf(p00, p01), best[0][r]);
      const float p10 = __uint_as_float((__float_as_uint(a10[r]) & 0xFFFFFFE0u) | sid0);
      const float p11 = __uint_as_float((__float_as_uint(a11[r]) & 0xFFFFFFE0u) | sid1);
      best[1][r] = fmaxf(fmaxf(p10, p11), best[1][r]);
    }
  }

  __syncthreads();  // ALL waves done reading ring; safe to reuse as qidx
  int* qidxL = (int*)ring;  // [256]

  // ---- epilogue: per-lane reduce over 16 regs + one cross-half exchange
  float ls = 0.f;
#pragma unroll
  for (int m = 0; m < 2; ++m) {
    float win = best[m][0];
    int wr = 0;
#pragma unroll
    for (int r = 1; r < 16; ++r) {
      const bool g = best[m][r] > win;  // tie -> keep lower r (smaller row)
      win = g ? best[m][r] : win;
      wr = g ? r : wr;
    }
    const unsigned u = __float_as_uint(win);
    const int t = 31 - (int)(u & 31u);
    int code = (t >> 1) * 64 + (t & 1) * 32 + ((wr & 3) + 8 * (wr >> 2) + 4 * half);
    float clean = __uint_as_float(u & 0xFFFFFFE0u);
    const float ocl = __shfl_xor(clean, 32);
    const int oc = __shfl_xor(code, 32);
    const bool take = (ocl > clean) || (ocl == clean && oc < code);
    clean = take ? ocl : clean;
    code = take ? oc : code;
    if (half == 0) {
      qidxL[w * 64 + m * 32 + col] = code;
      ls += xx[m] - 2.0f * clean;  // ||x||^2 - 2(x.c* - 0.5||c*||^2)
    }
  }
#pragma unroll
  for (int mk = 1; mk < 64; mk <<= 1) ls += __shfl_xor(ls, mk);
  if (l == 0) atomicAdd(&ws[LOSS_OFF + (blk & (NPART - 1))], ls);
  __syncthreads();  // qidxL visible to all threads

  // ---- fused output: histogram partial + gather + NCHW write (coalesced)
  const int ci = qidxL[tid];
  atomicAdd(ws + PART_OFF + (size_t)(blk & (NPART - 1)) * 1024 + ci, 1.0f);
  const float* crow = (ci < 512) ? (cb0 + (size_t)ci * 64) : (cb1 + (size_t)(ci - 512) * 64);
  float* ob = out + (((size_t)(bb * 64)) << 12) + hw0 + tid;
#pragma unroll
  for (int d4 = 0; d4 < 16; ++d4) {
    const float4 f = *(const float4*)(crow + d4 * 4);
    ob[((size_t)(d4 * 4 + 0)) << 12] = f.x;
    ob[((size_t)(d4 * 4 + 1)) << 12] = f.y;
    ob[((size_t)(d4 * 4 + 2)) << 12] = f.z;
    ob[((size_t)(d4 * 4 + 3)) << 12] = f.w;
  }
}

__global__ void vq_final(const float* __restrict__ ws, float* __restrict__ out) {
  __shared__ float sred[256];
  const int t = threadIdx.x;
  float h = 0.f;
#pragma unroll
  for (int i = t; i < 1024; i += 256) {
    float s = 0.f;
#pragma unroll
    for (int p = 0; p < NPART; ++p) s += ws[PART_OFF + p * 1024 + i];
    const float avg = s * (1.0f / 131072.0f);
    h += avg * logf(avg + 1e-10f);
  }
  sred[t] = h;
  __syncthreads();
  for (int s2 = 128; s2 > 0; s2 >>= 1) {
    if (t < s2) sred[t] += sred[t + s2];
    __syncthreads();
  }
  if (t == 0) {
    float lsum = 0.f;
#pragma unroll
    for (int p = 0; p < NPART; ++p) lsum += ws[LOSS_OFF + p];
    out[8388608] = 1.25f * lsum * (1.0f / 8388608.0f);
    out[8388609] = expf(-sred[0]);
  }
}

extern "C" void kernel_launch(void* const* d_in, const int* in_sizes, int n_in,
                              void* d_out, int out_size, void* d_ws, size_t ws_size,
                              hipStream_t stream) {
  (void)in_sizes; (void)n_in; (void)out_size; (void)ws_size;
  const float* xin = (const float*)d_in[0];
  const float* cb0 = (const float*)d_in[1];
  const float* cb1 = (const float*)d_in[2];
  const int* idxp = (const int*)d_in[3];
  float* out = (float*)d_out;
  float* ws = (float*)d_ws;

  vq_pack<<<4, 256, 0, stream>>>(cb0, cb1, ws);
  vq_dist<<<512, 256, 0, stream>>>(xin, idxp, cb0, cb1, out, ws);
  vq_final<<<1, 256, 0, stream>>>(ws, out);
}